// Round 14
// baseline (118.862 us; speedup 1.0000x reference)
//
#include <hip/hip_runtime.h>
#include <math.h>

// Problem constants
#define KC 1024       // num codes
#define DD 256        // embedding dim
#define NROWS 32768   // 32 * 32 * 32 (B*H*W)
#define NELEM 8388608 // NROWS * DD

typedef _Float16 f16;
typedef __attribute__((ext_vector_type(8))) _Float16 f16x8;
typedef __attribute__((ext_vector_type(16))) float f32x16;

#define KEY_SCALE 2097152.0f   // 2^21; |score| <= ~0.63 -> |ikey| < 2^21
#define KEY_INV   (1.0f / 2097152.0f)

// ---------------------------------------------------------------------------
// prep: c_sq (exact fp32) + emb -> fp16 swizzled + stat_done = 0.
// grid 256 x 256.  emb_h layout: [kg 32][code 1024][8]
// ---------------------------------------------------------------------------
__global__ void vq_prep_kernel(const float* __restrict__ emb, f16* __restrict__ emb_h,
                               float* __restrict__ c_sq, unsigned* __restrict__ stat_done) {
    const int tid = threadIdx.x;
    const int gt = blockIdx.x * 256 + tid;
    if (gt == 0) *stat_done = 0u;
    {
        int k = blockIdx.x * 4 + (tid >> 6);
        int lane = tid & 63;
        float4 v = *(const float4*)(emb + (size_t)k * DD + lane * 4);
        float s = v.x * v.x + v.y * v.y + v.z * v.z + v.w * v.w;
        #pragma unroll
        for (int off = 32; off > 0; off >>= 1) s += __shfl_down(s, off);
        if (lane == 0) c_sq[k] = s;
    }
    if (gt < 32768) {
        int code = gt & 1023;
        int kg = gt >> 10;
        const float* p = emb + (size_t)code * DD + kg * 8;
        float4 v0 = *(const float4*)p;
        float4 v1 = *(const float4*)(p + 4);
        f16x8 hcv;
        hcv[0] = (f16)v0.x; hcv[1] = (f16)v0.y; hcv[2] = (f16)v0.z; hcv[3] = (f16)v0.w;
        hcv[4] = (f16)v1.x; hcv[5] = (f16)v1.y; hcv[6] = (f16)v1.z; hcv[7] = (f16)v1.w;
        *(f16x8*)(emb_h + (size_t)gt * 8) = hcv;
    }
}

// ---------------------------------------------------------------------------
// K1 FUSED: argmin + gather + transpose-write. grid 256, 512 threads,
// 128 rows/block, all 1024 codes/block (R13's proven compute structure,
// Phases A/B verbatim). After Phase B the 64KB z_s buffer is dead -> reused
// as Qt[128][65] staging in 4 quadrant passes (row-half x channel-half):
// stage 64 rows x 128 ch of emb[idx] from L2 (64B/lane, conflict-free
// scatter), drain full 256B out lines (K2-writer pattern verbatim). This
// removes the 1024-block writer dispatch and its idx_g reload entirely.
// SPILL LANDMINES (do not retry): R9's manual 2-deep load pipeline and
// R10's csq_s LDS table both collapsed the allocator -> 100MB+ scratch.
// c_sq loads stay IN-PLACE; #pragma unroll 2; no rotation registers;
// Phase C adds no live state across the MFMA body (strictly after it).
// Outputs: out (32MB), idx_g (for stats), loss_blk[bid]. Zero atomics.
// argmin key = trunc(score*2^21)*1024 + code (monotone, first-min ties;
// math identical to R13 -> bitwise-identical keys/absmax).
// ---------------------------------------------------------------------------
__global__ __launch_bounds__(512, 4)
void vq_main_kernel(const float* __restrict__ z, const float* __restrict__ emb,
                    const f16* __restrict__ emb_h, const float* __restrict__ c_sq,
                    int* __restrict__ idx_g, float* __restrict__ loss_blk,
                    float* __restrict__ out) {
    __shared__ __align__(16) char smem[65536];        // z_s (A/B) then Qt (C)
    __shared__ int   bl_key[8][128];                  // 4096 B
    __shared__ float zsq_part[8][128];                // 4096 B
    __shared__ int   idx_s[128];                      // 512 B
    __shared__ float lsum2[2];

    f16* z_s = (f16*)smem;            // [kg 32][row 128][8] = 65536 B
    float (*Qt)[65] = (float(*)[65])smem;  // [ch 128][row 65] = 33280 B (C reuse)

    const int tid = threadIdx.x;
    const int n0 = blockIdx.x * 128;   // 128-row tile; never straddles an image
    const int b = n0 >> 10;
    const int hw0 = n0 & 1023;

    // ---- Phase A: stage 128-row z tile fp16 + per-row ||z||^2 partials ----
    {
        const int r2 = tid & 63;
        const int kq = tid >> 6;  // 0..7
        #pragma unroll
        for (int rh = 0; rh < 2; ++rh) {
            const int r = rh * 64 + r2;
            const float* zp = z + (size_t)b * (DD * 1024) + hw0 + r;
            float sq = 0.f;
            #pragma unroll
            for (int it = 0; it < 4; ++it) {
                int kg = kq * 4 + it;
                f16x8 hv;
                #pragma unroll
                for (int j = 0; j < 8; ++j) {
                    float v = zp[(size_t)(kg * 8 + j) * 1024];
                    sq += v * v;
                    hv[j] = (f16)v;
                }
                *(f16x8*)&z_s[(kg * 128 + r) * 8] = hv;
            }
            zsq_part[kq][r] = sq;
        }
    }
    __syncthreads();

    const int m = tid & 31;        // lane -> z row within each 32-row group
    const int h = (tid >> 5) & 1;  // k-half; also selects code subset (+4h)
    const int w = tid >> 6;        // wave id 0..7

    int kmin0 = 0x7FFFFFFF;        // rows m
    int kmin1 = 0x7FFFFFFF;        // rows m+32
    int kmin2 = 0x7FFFFFFF;        // rows m+64
    int kmin3 = 0x7FFFFFFF;        // rows m+96

    // ---- Phase B: wave owns 128 codes as 4 chunks of 32; 4 row-groups ----
    for (int c = 0; c < 4; ++c) {
        const int cb = w * 128 + c * 32;               // chunk base code
        const f16* ebp = emb_h + (size_t)h * 8192 + (size_t)(cb + m) * 8;

        f32x16 acc0, acc1, acc2, acc3;  // D[code][row] per 32-row group
        #pragma unroll
        for (int i = 0; i < 16; ++i) {
            acc0[i] = 0.f; acc1[i] = 0.f; acc2[i] = 0.f; acc3[i] = 0.f;
        }

        #pragma unroll 2
        for (int ks = 0; ks < 16; ++ks) {
            const f16* za = z_s + ((size_t)(2 * ks + h) * 128 + m) * 8;
            f16x8 zb0 = *(const f16x8*)(za);           // rows 0-31
            f16x8 zb1 = *(const f16x8*)(za + 256);     // rows 32-63
            f16x8 zb2 = *(const f16x8*)(za + 512);     // rows 64-95
            f16x8 zb3 = *(const f16x8*)(za + 768);     // rows 96-127
            f16x8 ea  = *(const f16x8*)(ebp + (size_t)ks * 16384); // emb (A frag)
            acc0 = __builtin_amdgcn_mfma_f32_32x32x16_f16(ea, zb0, acc0, 0, 0, 0);
            acc1 = __builtin_amdgcn_mfma_f32_32x32x16_f16(ea, zb1, acc1, 0, 0, 0);
            acc2 = __builtin_amdgcn_mfma_f32_32x32x16_f16(ea, zb2, acc2, 0, 0, 0);
            acc3 = __builtin_amdgcn_mfma_f32_32x32x16_f16(ea, zb3, acc3, 0, 0, 0);
        }

        // in-register argmin over the 16 codes this lane holds (c_sq in-place)
        #pragma unroll
        for (int reg = 0; reg < 16; ++reg) {
            int code = cb + (reg & 3) + 8 * (reg >> 2) + 4 * h;
            float cs = c_sq[code];
            float s0 = fmaf(-2.f, acc0[reg], cs);
            float s1 = fmaf(-2.f, acc1[reg], cs);
            float s2 = fmaf(-2.f, acc2[reg], cs);
            float s3 = fmaf(-2.f, acc3[reg], cs);
            kmin0 = min(kmin0, (int)(s0 * KEY_SCALE) * 1024 + code);
            kmin1 = min(kmin1, (int)(s1 * KEY_SCALE) * 1024 + code);
            kmin2 = min(kmin2, (int)(s2 * KEY_SCALE) * 1024 + code);
            kmin3 = min(kmin3, (int)(s3 * KEY_SCALE) * 1024 + code);
        }
    }

    // merge lane-halves (lanes m and m+32 hold the same z row, disjoint codes)
    kmin0 = min(kmin0, __shfl_xor(kmin0, 32));
    kmin1 = min(kmin1, __shfl_xor(kmin1, 32));
    kmin2 = min(kmin2, __shfl_xor(kmin2, 32));
    kmin3 = min(kmin3, __shfl_xor(kmin3, 32));
    if (h == 0) {
        bl_key[w][m]      = kmin0;
        bl_key[w][32 + m] = kmin1;
        bl_key[w][64 + m] = kmin2;
        bl_key[w][96 + m] = kmin3;
    }
    __syncthreads();

    // ---- combine 8 waves -> idx (LDS + global) + per-block loss ----
    if (tid < 128) {
        int k = bl_key[0][tid];
        #pragma unroll
        for (int w2 = 1; w2 < 8; ++w2) k = min(k, bl_key[w2][tid]);
        int i = k & 1023;               // low 10 bits = code
        idx_s[tid] = i;
        idx_g[n0 + tid] = i;
        float zq = 0.f;
        #pragma unroll
        for (int p = 0; p < 8; ++p) zq += zsq_part[p][tid];
        float lr = (float)(k >> 10) * KEY_INV + zq;  // score_min + ||z||^2
        #pragma unroll
        for (int off = 32; off > 0; off >>= 1) lr += __shfl_down(lr, off);
        if ((tid & 63) == 0) lsum2[tid >> 6] = lr;
    }
    __syncthreads();
    if (tid == 0) loss_blk[blockIdx.x] = lsum2[0] + lsum2[1];   // NO atomic

    // ---- Phase C: gather+transpose-write, 4 quadrants (row-half x ch-half)
    // z_s is dead; reuse as Qt[128][65]. K2-writer pattern verbatim.
    #pragma unroll
    for (int q = 0; q < 4; ++q) {
        const int rh = q >> 1;          // row-half 0..1
        const int ch0 = (q & 1) * 128;  // channel-half base
        // stage: thread (p=tid>>6, r=tid&63) loads emb[idx[rh*64+r]][ch0+p*16..+16]
        {
            int r = tid & 63;
            int p = tid >> 6;
            const float* ep = emb + (size_t)idx_s[rh * 64 + r] * DD + ch0 + p * 16;
            float4 v0 = *(const float4*)(ep);
            float4 v1 = *(const float4*)(ep + 4);
            float4 v2 = *(const float4*)(ep + 8);
            float4 v3 = *(const float4*)(ep + 12);
            float vv[16] = {v0.x, v0.y, v0.z, v0.w, v1.x, v1.y, v1.z, v1.w,
                            v2.x, v2.y, v2.z, v2.w, v3.x, v3.y, v3.z, v3.w};
            #pragma unroll
            for (int g = 0; g < 16; ++g)
                Qt[p * 16 + g][r] = vv[g];   // lanes r consecutive -> conflict-free
        }
        __syncthreads();
        // drain: wave w covers 16 channels; per channel 64 lanes write one
        // full 256B contiguous line of out.
        {
            int lane = tid & 63;
            const size_t base = (size_t)b * (DD * 1024) + hw0 + rh * 64 + lane;
            #pragma unroll
            for (int g = 0; g < 16; ++g) {
                int ch = w * 16 + g;
                out[base + (size_t)(ch0 + ch) * 1024] = Qt[ch][lane];
            }
        }
        __syncthreads();
    }
}

// ---------------------------------------------------------------------------
// K2 stats: grid 8 (R12's proven parallel-stat pattern, writers removed).
// Block j LDS-histograms rows [j*4096,(j+1)*4096) of idx_g, stores its
// 1024-bin partial; last arriver (done race, threadfence release/acquire +
// atomic reads) combines partials -> entropy, sums loss_blk[256] -> loss.
// ---------------------------------------------------------------------------
__global__ __launch_bounds__(512, 4)
void vq_stat_kernel(const int* __restrict__ idx_g, const float* __restrict__ loss_blk,
                    int* __restrict__ hist_g, unsigned* __restrict__ stat_done,
                    float* __restrict__ out_tail) {
    __shared__ int   hist[KC];
    __shared__ float wsum[8];
    __shared__ float lsumw[8];
    __shared__ int   flag_s;

    const int tid = threadIdx.x;
    const int j = blockIdx.x;

    for (int k = tid; k < KC; k += 512) hist[k] = 0;
    __syncthreads();
    #pragma unroll
    for (int it = 0; it < 8; ++it)
        atomicAdd(&hist[idx_g[j * 4096 + it * 512 + tid]], 1);  // LDS atomic
    __syncthreads();
    for (int k = tid; k < KC; k += 512) hist_g[j * KC + k] = hist[k];
    __threadfence();                 // release partial before signaling
    if (tid == 0) flag_s = (atomicAdd(stat_done, 1u) == 7u) ? 1 : 0;
    __syncthreads();
    if (!flag_s) return;
    __threadfence();                 // acquire others' partials

    float s = 0.f;
    for (int k = tid; k < KC; k += 512) {
        int c = 0;
        #pragma unroll
        for (int p = 0; p < 8; ++p) c += atomicAdd(&hist_g[p * KC + k], 0);
        float pr = (float)c * (1.0f / (float)NROWS);
        s += pr * logf(pr + 1e-10f);
    }
    float lv = (tid < 256) ? loss_blk[tid] : 0.f;  // 256 partials from K1
    #pragma unroll
    for (int off = 32; off > 0; off >>= 1) {
        s  += __shfl_down(s, off);
        lv += __shfl_down(lv, off);
    }
    if ((tid & 63) == 0) { wsum[tid >> 6] = s; lsumw[tid >> 6] = lv; }
    __syncthreads();
    if (tid == 0) {
        float ent = 0.f, loss_tot = 0.f;
        #pragma unroll
        for (int p = 0; p < 8; ++p) { ent += wsum[p]; loss_tot += lsumw[p]; }
        out_tail[0] = 1.25f * loss_tot * (1.0f / (float)NELEM);
        out_tail[1] = expf(-ent);
    }
}

// ---------------------------------------------------------------------------
extern "C" void kernel_launch(void* const* d_in, const int* in_sizes, int n_in,
                              void* d_out, int out_size, void* d_ws, size_t ws_size,
                              hipStream_t stream) {
    const float* z = (const float*)d_in[0];    // (32,256,32,32)
    const float* emb = (const float*)d_in[1];  // (1024,256)
    float* out = (float*)d_out;                // 8388608 + 2

    char* wsb = (char*)d_ws;
    f16* emb_h = (f16*)wsb;                        // 524288 B
    float* c_sq = (float*)(wsb + 524288);          // 4096 B
    int* idx_g = (int*)(wsb + 528384);             // 131072 B
    float* loss_blk = (float*)(wsb + 659456);      // 1024 B (256 blocks)
    int* hist_g = (int*)(wsb + 661504);            // 32768 B
    unsigned* stat_done = (unsigned*)(wsb + 694272); // 4 B

    hipLaunchKernelGGL(vq_prep_kernel, dim3(256), dim3(256), 0, stream,
                       emb, emb_h, c_sq, stat_done);
    hipLaunchKernelGGL(vq_main_kernel, dim3(256), dim3(512), 0, stream,
                       z, emb, emb_h, c_sq, idx_g, loss_blk, out);
    hipLaunchKernelGGL(vq_stat_kernel, dim3(8), dim3(512), 0, stream,
                       idx_g, loss_blk, hist_g, stat_done, out + NELEM);
}

// Round 16
// 118.823 us; speedup vs baseline: 1.0003x; 1.0003x over previous
//
#include <hip/hip_runtime.h>
#include <math.h>

// Problem constants
#define KC 1024       // num codes
#define DD 256        // embedding dim
#define NROWS 32768   // 32 * 32 * 32 (B*H*W)
#define NELEM 8388608 // NROWS * DD

typedef _Float16 f16;
typedef __attribute__((ext_vector_type(8))) _Float16 f16x8;
typedef __attribute__((ext_vector_type(16))) float f32x16;

#define KEY_SCALE 2097152.0f   // 2^21; |score| <= ~0.63 -> |ikey| < 2^21
#define KEY_INV   (1.0f / 2097152.0f)

// ---------------------------------------------------------------------------
// prep: c_sq (exact fp32) + emb -> fp16 swizzled + stat_done = 0.
// grid 256 x 256.  emb_h layout: [kg 32][code 1024][8]
// ---------------------------------------------------------------------------
__global__ void vq_prep_kernel(const float* __restrict__ emb, f16* __restrict__ emb_h,
                               float* __restrict__ c_sq, unsigned* __restrict__ stat_done) {
    const int tid = threadIdx.x;
    const int gt = blockIdx.x * 256 + tid;
    if (gt == 0) *stat_done = 0u;
    {
        int k = blockIdx.x * 4 + (tid >> 6);
        int lane = tid & 63;
        float4 v = *(const float4*)(emb + (size_t)k * DD + lane * 4);
        float s = v.x * v.x + v.y * v.y + v.z * v.z + v.w * v.w;
        #pragma unroll
        for (int off = 32; off > 0; off >>= 1) s += __shfl_down(s, off);
        if (lane == 0) c_sq[k] = s;
    }
    if (gt < 32768) {
        int code = gt & 1023;
        int kg = gt >> 10;
        const float* p = emb + (size_t)code * DD + kg * 8;
        float4 v0 = *(const float4*)p;
        float4 v1 = *(const float4*)(p + 4);
        f16x8 hcv;
        hcv[0] = (f16)v0.x; hcv[1] = (f16)v0.y; hcv[2] = (f16)v0.z; hcv[3] = (f16)v0.w;
        hcv[4] = (f16)v1.x; hcv[5] = (f16)v1.y; hcv[6] = (f16)v1.z; hcv[7] = (f16)v1.w;
        *(f16x8*)(emb_h + (size_t)gt * 8) = hcv;
    }
}

// ---------------------------------------------------------------------------
// K1 FUSED: argmin + gather + transpose-write. grid 256, **1024 threads
// (16 waves)** — R14's fused kernel ran 1 block/CU with only 8 waves/CU
// (Occupancy 19.9%), latency-bound in every phase. Doubling waves (not
// blocks) keeps the 128-row tile and the 4-MFMAs-per-ea-load intensity:
//   Phase B: wave w (0..15) owns 64 codes as 2 chunks of 32 (union over
//   waves identical to R13/R14; keys unique + min associative -> bitwise-
//   identical argmin). Per-wave reg state unchanged (4 acc + 4 kmin).
//   Phases A/C: same totals over 2x threads -> per-thread work halves.
// SPILL LANDMINES (do not retry): R9's manual 2-deep load pipeline and
// R10's csq_s LDS table both collapsed the allocator -> 100MB+ scratch.
// c_sq loads stay IN-PLACE; #pragma unroll 2; no rotation registers;
// Phase C adds no live state across the MFMA body. launch_bounds(1024,4)
// -> 128-reg cap, fits the ~110-reg state (same regime as clean R13).
// Outputs: out (32MB), idx_g (for stats), loss_blk[bid]. Zero atomics.
// argmin key = trunc(score*2^21)*1024 + code (monotone, first-min ties).
// ---------------------------------------------------------------------------
__global__ __launch_bounds__(1024, 4)
void vq_main_kernel(const float* __restrict__ z, const float* __restrict__ emb,
                    const f16* __restrict__ emb_h, const float* __restrict__ c_sq,
                    int* __restrict__ idx_g, float* __restrict__ loss_blk,
                    float* __restrict__ out) {
    __shared__ __align__(16) char smem[65536];        // z_s (A/B) then Qt (C)
    __shared__ int   bl_key[16][128];                 // 8192 B
    __shared__ float zsq_part[8][128];                // 4096 B
    __shared__ int   idx_s[128];                      // 512 B
    __shared__ float lsum2[2];

    f16* z_s = (f16*)smem;            // [kg 32][row 128][8] = 65536 B
    float (*Qt)[65] = (float(*)[65])smem;  // [ch 128][row 65] = 33280 B (C reuse)

    const int tid = threadIdx.x;
    const int n0 = blockIdx.x * 128;   // 128-row tile; never straddles an image
    const int b = n0 >> 10;
    const int hw0 = n0 & 1023;

    // ---- Phase A: stage 128-row z tile fp16 + per-row ||z||^2 partials ----
    {
        const int r = tid & 127;       // row
        const int kq = tid >> 7;       // 0..7, each covers 32 channels (4 kgs)
        const float* zp = z + (size_t)b * (DD * 1024) + hw0 + r;
        float sq = 0.f;
        #pragma unroll
        for (int it = 0; it < 4; ++it) {
            int kg = kq * 4 + it;
            f16x8 hv;
            #pragma unroll
            for (int j = 0; j < 8; ++j) {
                float v = zp[(size_t)(kg * 8 + j) * 1024];
                sq += v * v;
                hv[j] = (f16)v;
            }
            *(f16x8*)&z_s[(kg * 128 + r) * 8] = hv;
        }
        zsq_part[kq][r] = sq;
    }
    __syncthreads();

    const int m = tid & 31;        // lane -> z row within each 32-row group
    const int h = (tid >> 5) & 1;  // k-half; also selects code subset (+4h)
    const int w = tid >> 6;        // wave id 0..15

    int kmin0 = 0x7FFFFFFF;        // rows m
    int kmin1 = 0x7FFFFFFF;        // rows m+32
    int kmin2 = 0x7FFFFFFF;        // rows m+64
    int kmin3 = 0x7FFFFFFF;        // rows m+96

    // ---- Phase B: wave owns 64 codes as 2 chunks of 32; 4 row-groups ----
    for (int c = 0; c < 2; ++c) {
        const int cb = w * 64 + c * 32;                // chunk base code
        const f16* ebp = emb_h + (size_t)h * 8192 + (size_t)(cb + m) * 8;

        f32x16 acc0, acc1, acc2, acc3;  // D[code][row] per 32-row group
        #pragma unroll
        for (int i = 0; i < 16; ++i) {
            acc0[i] = 0.f; acc1[i] = 0.f; acc2[i] = 0.f; acc3[i] = 0.f;
        }

        #pragma unroll 2
        for (int ks = 0; ks < 16; ++ks) {
            const f16* za = z_s + ((size_t)(2 * ks + h) * 128 + m) * 8;
            f16x8 zb0 = *(const f16x8*)(za);           // rows 0-31
            f16x8 zb1 = *(const f16x8*)(za + 256);     // rows 32-63
            f16x8 zb2 = *(const f16x8*)(za + 512);     // rows 64-95
            f16x8 zb3 = *(const f16x8*)(za + 768);     // rows 96-127
            f16x8 ea  = *(const f16x8*)(ebp + (size_t)ks * 16384); // emb (A frag)
            acc0 = __builtin_amdgcn_mfma_f32_32x32x16_f16(ea, zb0, acc0, 0, 0, 0);
            acc1 = __builtin_amdgcn_mfma_f32_32x32x16_f16(ea, zb1, acc1, 0, 0, 0);
            acc2 = __builtin_amdgcn_mfma_f32_32x32x16_f16(ea, zb2, acc2, 0, 0, 0);
            acc3 = __builtin_amdgcn_mfma_f32_32x32x16_f16(ea, zb3, acc3, 0, 0, 0);
        }

        // in-register argmin over the 16 codes this lane holds (c_sq in-place)
        #pragma unroll
        for (int reg = 0; reg < 16; ++reg) {
            int code = cb + (reg & 3) + 8 * (reg >> 2) + 4 * h;
            float cs = c_sq[code];
            float s0 = fmaf(-2.f, acc0[reg], cs);
            float s1 = fmaf(-2.f, acc1[reg], cs);
            float s2 = fmaf(-2.f, acc2[reg], cs);
            float s3 = fmaf(-2.f, acc3[reg], cs);
            kmin0 = min(kmin0, (int)(s0 * KEY_SCALE) * 1024 + code);
            kmin1 = min(kmin1, (int)(s1 * KEY_SCALE) * 1024 + code);
            kmin2 = min(kmin2, (int)(s2 * KEY_SCALE) * 1024 + code);
            kmin3 = min(kmin3, (int)(s3 * KEY_SCALE) * 1024 + code);
        }
    }

    // merge lane-halves (lanes m and m+32 hold the same z row, disjoint codes)
    kmin0 = min(kmin0, __shfl_xor(kmin0, 32));
    kmin1 = min(kmin1, __shfl_xor(kmin1, 32));
    kmin2 = min(kmin2, __shfl_xor(kmin2, 32));
    kmin3 = min(kmin3, __shfl_xor(kmin3, 32));
    if (h == 0) {
        bl_key[w][m]      = kmin0;
        bl_key[w][32 + m] = kmin1;
        bl_key[w][64 + m] = kmin2;
        bl_key[w][96 + m] = kmin3;
    }
    __syncthreads();

    // ---- combine 16 waves -> idx (LDS + global) + per-block loss ----
    if (tid < 128) {
        int k = bl_key[0][tid];
        #pragma unroll
        for (int w2 = 1; w2 < 16; ++w2) k = min(k, bl_key[w2][tid]);
        int i = k & 1023;               // low 10 bits = code
        idx_s[tid] = i;
        idx_g[n0 + tid] = i;
        float zq = 0.f;
        #pragma unroll
        for (int p = 0; p < 8; ++p) zq += zsq_part[p][tid];
        float lr = (float)(k >> 10) * KEY_INV + zq;  // score_min + ||z||^2
        #pragma unroll
        for (int off = 32; off > 0; off >>= 1) lr += __shfl_down(lr, off);
        if ((tid & 63) == 0) lsum2[tid >> 6] = lr;
    }
    __syncthreads();
    if (tid == 0) loss_blk[blockIdx.x] = lsum2[0] + lsum2[1];   // NO atomic

    // ---- Phase C: gather+transpose-write, 4 quadrants (row-half x ch-half)
    // z_s is dead; reuse as Qt[128][65]. 1024 threads: per quadrant each
    // thread stages 8 floats (p=tid>>6 covers 8 channels), each of 16 waves
    // drains 8 full 256B out lines.
    #pragma unroll
    for (int q = 0; q < 4; ++q) {
        const int rh = q >> 1;          // row-half 0..1
        const int ch0 = (q & 1) * 128;  // channel-half base
        {
            int r = tid & 63;
            int p = tid >> 6;           // 0..15 -> 8 channels each
            const float* ep = emb + (size_t)idx_s[rh * 64 + r] * DD + ch0 + p * 8;
            float4 v0 = *(const float4*)(ep);
            float4 v1 = *(const float4*)(ep + 4);
            float vv[8] = {v0.x, v0.y, v0.z, v0.w, v1.x, v1.y, v1.z, v1.w};
            #pragma unroll
            for (int g = 0; g < 8; ++g)
                Qt[p * 8 + g][r] = vv[g];   // lanes r consecutive -> conflict-free
        }
        __syncthreads();
        {
            int lane = tid & 63;
            const size_t base = (size_t)b * (DD * 1024) + hw0 + rh * 64 + lane;
            #pragma unroll
            for (int g = 0; g < 8; ++g) {
                int ch = w * 8 + g;
                out[base + (size_t)(ch0 + ch) * 1024] = Qt[ch][lane];
            }
        }
        __syncthreads();
    }
}

// ---------------------------------------------------------------------------
// K2 stats: grid 8 (R12's proven parallel-stat pattern). Block j LDS-
// histograms rows [j*4096,(j+1)*4096) of idx_g, stores its 1024-bin partial;
// last arriver (done race, threadfence release/acquire + atomic reads)
// combines partials -> entropy, sums loss_blk[256] -> loss.
// ---------------------------------------------------------------------------
__global__ __launch_bounds__(512, 4)
void vq_stat_kernel(const int* __restrict__ idx_g, const float* __restrict__ loss_blk,
                    int* __restrict__ hist_g, unsigned* __restrict__ stat_done,
                    float* __restrict__ out_tail) {
    __shared__ int   hist[KC];
    __shared__ float wsum[8];
    __shared__ float lsumw[8];
    __shared__ int   flag_s;

    const int tid = threadIdx.x;
    const int j = blockIdx.x;

    for (int k = tid; k < KC; k += 512) hist[k] = 0;
    __syncthreads();
    #pragma unroll
    for (int it = 0; it < 8; ++it)
        atomicAdd(&hist[idx_g[j * 4096 + it * 512 + tid]], 1);  // LDS atomic
    __syncthreads();
    for (int k = tid; k < KC; k += 512) hist_g[j * KC + k] = hist[k];
    __threadfence();                 // release partial before signaling
    if (tid == 0) flag_s = (atomicAdd(stat_done, 1u) == 7u) ? 1 : 0;
    __syncthreads();
    if (!flag_s) return;
    __threadfence();                 // acquire others' partials

    float s = 0.f;
    for (int k = tid; k < KC; k += 512) {
        int c = 0;
        #pragma unroll
        for (int p = 0; p < 8; ++p) c += atomicAdd(&hist_g[p * KC + k], 0);
        float pr = (float)c * (1.0f / (float)NROWS);
        s += pr * logf(pr + 1e-10f);
    }
    float lv = (tid < 256) ? loss_blk[tid] : 0.f;  // 256 partials from K1
    #pragma unroll
    for (int off = 32; off > 0; off >>= 1) {
        s  += __shfl_down(s, off);
        lv += __shfl_down(lv, off);
    }
    if ((tid & 63) == 0) { wsum[tid >> 6] = s; lsumw[tid >> 6] = lv; }
    __syncthreads();
    if (tid == 0) {
        float ent = 0.f, loss_tot = 0.f;
        #pragma unroll
        for (int p = 0; p < 8; ++p) { ent += wsum[p]; loss_tot += lsumw[p]; }
        out_tail[0] = 1.25f * loss_tot * (1.0f / (float)NELEM);
        out_tail[1] = expf(-ent);
    }
}

// ---------------------------------------------------------------------------
extern "C" void kernel_launch(void* const* d_in, const int* in_sizes, int n_in,
                              void* d_out, int out_size, void* d_ws, size_t ws_size,
                              hipStream_t stream) {
    const float* z = (const float*)d_in[0];    // (32,256,32,32)
    const float* emb = (const float*)d_in[1];  // (1024,256)
    float* out = (float*)d_out;                // 8388608 + 2

    char* wsb = (char*)d_ws;
    f16* emb_h = (f16*)wsb;                        // 524288 B
    float* c_sq = (float*)(wsb + 524288);          // 4096 B
    int* idx_g = (int*)(wsb + 528384);             // 131072 B
    float* loss_blk = (float*)(wsb + 659456);      // 1024 B (256 blocks)
    int* hist_g = (int*)(wsb + 661504);            // 32768 B
    unsigned* stat_done = (unsigned*)(wsb + 694272); // 4 B

    hipLaunchKernelGGL(vq_prep_kernel, dim3(256), dim3(256), 0, stream,
                       emb, emb_h, c_sq, stat_done);
    hipLaunchKernelGGL(vq_main_kernel, dim3(256), dim3(1024), 0, stream,
                       z, emb, emb_h, c_sq, idx_g, loss_blk, out);
    hipLaunchKernelGGL(vq_stat_kernel, dim3(8), dim3(512), 0, stream,
                       idx_g, loss_blk, hist_g, stat_done, out + NELEM);
}